// Round 1
// baseline (285.193 us; speedup 1.0000x reference)
//
#include <hip/hip_runtime.h>

// CortexNetwork: aff + 0.9*exc - 0.9*inh, relu, broadcast over C.
// Memory-bound: each weight element read exactly once (~263 MB total).
// One 256-thread block per grid point (i,j); 1296 blocks.

constexpr int C   = 16;
constexpr int GX  = 36;
constexpr int GY  = 36;
constexpr int RF  = 24;
constexpr int IMG = 64;
constexpr int GG  = GX * GY;   // 1296
constexpr int RR  = RF * RF;   // 576

__global__ __launch_bounds__(256)
void cortex_kernel(const float* __restrict__ x,
                   const float* __restrict__ prev,
                   const float* __restrict__ affW,
                   const float* __restrict__ exW,
                   const float* __restrict__ inW,
                   const int*   __restrict__ rx,
                   const int*   __restrict__ ry,
                   float* __restrict__ out)
{
    const int bid = blockIdx.x;          // (i,j) grid point
    const int i = bid / GY;
    const int j = bid - i * GY;
    const int t = threadIdx.x;

    const int rxi = rx[i];
    const int ryj = ry[j];

    float acc = 0.0f;

    // ---- Afferent: sum_c sum_{u,v} x[c, rxi+u, ryj+v] * affW[c,i,j,u,v] ----
    // C*RR = 9216 = 36 * 256 exactly; affW reads are fully coalesced.
    {
        const size_t ij = (size_t)bid;   // i*GY + j
        for (int k = t; k < C * RR; k += 256) {
            const int c = k / RR;
            const int r = k - c * RR;
            const int u = r / RF;
            const int v = r - u * RF;
            const float w  = affW[((size_t)c * GG + ij) * RR + r];
            const float px = x[(c * IMG + rxi + u) * IMG + ryj + v];
            acc = fmaf(w, px, acc);
        }
    }

    // ---- Lateral: 0.9 * sum_c prev[c,i,j] * (rowsum(exW) - rowsum(inW)) ----
    // Each (c,i,j) row is 1296 contiguous floats = 324 float4 (16B aligned).
    {
        float lat = 0.0f;
        for (int c = 0; c < C; ++c) {
            const float p = prev[c * GG + bid];
            const size_t base = ((size_t)c * GG + bid) * GG;
            const float4* e4 = (const float4*)(exW + base);
            const float4* i4 = (const float4*)(inW + base);
            float s = 0.0f;
            for (int k = t; k < GG / 4; k += 256) {   // 324 vec4 elements
                const float4 a = e4[k];
                const float4 b = i4[k];
                s += (a.x + a.y + a.z + a.w) - (b.x + b.y + b.z + b.w);
            }
            lat = fmaf(p, s, lat);
        }
        acc = fmaf(0.9f, lat, acc);
    }

    // ---- Block reduction: wave shuffle (width 64) then cross-wave LDS ----
    for (int off = 32; off > 0; off >>= 1)
        acc += __shfl_down(acc, off, 64);

    __shared__ float sred[4];
    __shared__ float s_act;
    const int wave = t >> 6;
    const int lane = t & 63;
    if (lane == 0) sred[wave] = acc;
    __syncthreads();
    if (t == 0) {
        const float tot = sred[0] + sred[1] + sred[2] + sred[3];
        s_act = fmaxf(tot, 0.0f);
    }
    __syncthreads();

    // Broadcast to all C channels: out[c, i, j]
    if (t < C)
        out[t * GG + bid] = s_act;
}

extern "C" void kernel_launch(void* const* d_in, const int* in_sizes, int n_in,
                              void* d_out, int out_size, void* d_ws, size_t ws_size,
                              hipStream_t stream) {
    const float* x     = (const float*)d_in[0];
    const float* prev  = (const float*)d_in[1];
    const float* affW  = (const float*)d_in[2];
    const float* exW   = (const float*)d_in[3];
    const float* inW   = (const float*)d_in[4];
    const int*   rx    = (const int*)d_in[5];
    const int*   ry    = (const int*)d_in[6];
    float* out = (float*)d_out;

    cortex_kernel<<<GG, 256, 0, stream>>>(x, prev, affW, exW, inW, rx, ry, out);
}

// Round 2
// 273.301 us; speedup vs baseline: 1.0435x; 1.0435x over previous
//
#include <hip/hip_runtime.h>

// CortexNetwork: aff + 0.9*exc - 0.9*inh, relu, broadcast over C.
// R1 post-mortem: 113us @ 1.2TB/s, VGPR=16 -> latency-bound (no MLP).
// R2: split c-range across 4 blocks per (i,j) (5184 blocks), manually batch
// 8 independent float4 loads per iteration to force deep MLP, two-phase
// reduction through d_ws (no atomics).

constexpr int C   = 16;
constexpr int GX  = 36;
constexpr int GY  = 36;
constexpr int RF  = 24;
constexpr int IMG = 64;
constexpr int GG  = GX * GY;   // 1296
constexpr int RR  = RF * RF;   // 576
constexpr int SPLIT = 4;
constexpr int CPB   = C / SPLIT;   // 4 channels per block

__global__ __launch_bounds__(256)
void cortex_phase1(const float* __restrict__ x,
                   const float* __restrict__ prev,
                   const float* __restrict__ affW,
                   const float* __restrict__ exW,
                   const float* __restrict__ inW,
                   const int*   __restrict__ rx,
                   const int*   __restrict__ ry,
                   float* __restrict__ partial)
{
    const int bid   = blockIdx.x;
    const int ij    = bid % GG;
    const int split = bid / GG;
    const int cs    = split * CPB;
    const int i = ij / GY;
    const int j = ij - i * GY;
    const int t = threadIdx.x;

    const int rxi = rx[i];
    const int ryj = ry[j];

    float acc = 0.0f;

    // ---- Afferent: 4 channels x 144 float4 of affW; x via L1/L2 ----
    // RR/4 = 144 <= 256: threads t<144 each do one float4 per channel.
    if (t < RR / 4) {
        const int u  = t / (RF / 4);            // float4 index -> (u, v0)
        const int v0 = 4 * (t - u * (RF / 4));
        float4 w[CPB];
        #pragma unroll
        for (int cc = 0; cc < CPB; ++cc) {
            const int c = cs + cc;
            w[cc] = ((const float4*)(affW + ((size_t)c * GG + ij) * RR))[t];
        }
        #pragma unroll
        for (int cc = 0; cc < CPB; ++cc) {
            const int c = cs + cc;
            const float* xp = x + ((c * IMG + rxi + u) * IMG + ryj + v0);
            acc = fmaf(w[cc].x, xp[0], acc);
            acc = fmaf(w[cc].y, xp[1], acc);
            acc = fmaf(w[cc].z, xp[2], acc);
            acc = fmaf(w[cc].w, xp[3], acc);
        }
    }

    // ---- Lateral: 4 channels x 324 float4 from each of exW, inW ----
    // 8 independent float4 loads per iteration -> deep MLP.
    float d[CPB] = {0.0f, 0.0f, 0.0f, 0.0f};
    for (int k = t; k < GG / 4; k += 256) {
        float4 e[CPB], h[CPB];
        #pragma unroll
        for (int cc = 0; cc < CPB; ++cc) {
            const size_t base = ((size_t)(cs + cc) * GG + ij) * GG;
            e[cc] = ((const float4*)(exW + base))[k];
            h[cc] = ((const float4*)(inW + base))[k];
        }
        #pragma unroll
        for (int cc = 0; cc < CPB; ++cc)
            d[cc] += (e[cc].x + e[cc].y + e[cc].z + e[cc].w)
                   - (h[cc].x + h[cc].y + h[cc].z + h[cc].w);
    }
    {
        float lat = 0.0f;
        #pragma unroll
        for (int cc = 0; cc < CPB; ++cc)
            lat = fmaf(prev[(cs + cc) * GG + ij], d[cc], lat);
        acc = fmaf(0.9f, lat, acc);
    }

    // ---- Block reduction ----
    for (int off = 32; off > 0; off >>= 1)
        acc += __shfl_down(acc, off, 64);

    __shared__ float sred[4];
    const int wave = t >> 6;
    const int lane = t & 63;
    if (lane == 0) sred[wave] = acc;
    __syncthreads();
    if (t == 0)
        partial[split * GG + ij] = sred[0] + sred[1] + sred[2] + sred[3];
}

__global__ __launch_bounds__(256)
void cortex_phase2(const float* __restrict__ partial, float* __restrict__ out)
{
    const int ij = blockIdx.x * blockDim.x + threadIdx.x;
    if (ij < GG) {
        const float tot = partial[ij] + partial[GG + ij]
                        + partial[2 * GG + ij] + partial[3 * GG + ij];
        const float a = fmaxf(tot, 0.0f);
        #pragma unroll
        for (int c = 0; c < C; ++c)
            out[c * GG + ij] = a;
    }
}

extern "C" void kernel_launch(void* const* d_in, const int* in_sizes, int n_in,
                              void* d_out, int out_size, void* d_ws, size_t ws_size,
                              hipStream_t stream) {
    const float* x     = (const float*)d_in[0];
    const float* prev  = (const float*)d_in[1];
    const float* affW  = (const float*)d_in[2];
    const float* exW   = (const float*)d_in[3];
    const float* inW   = (const float*)d_in[4];
    const int*   rx    = (const int*)d_in[5];
    const int*   ry    = (const int*)d_in[6];
    float* out     = (float*)d_out;
    float* partial = (float*)d_ws;   // SPLIT * GG floats

    cortex_phase1<<<GG * SPLIT, 256, 0, stream>>>(x, prev, affW, exW, inW, rx, ry, partial);
    cortex_phase2<<<(GG + 255) / 256, 256, 0, stream>>>(partial, out);
}

// Round 3
// 245.946 us; speedup vs baseline: 1.1596x; 1.1112x over previous
//
#include <hip/hip_runtime.h>

// CortexNetwork: aff + 0.9*exc - 0.9*inh, relu, broadcast over C.
// R2 post-mortem: 101us, 2.6 TB/s CU-ingress (~4.3 B/cyc/CU), invariant to
// occupancy -> per-CU L1-miss-concurrency (MSHR) limited on single-use data.
// R3: nontemporal loads for the weight streams (bypass L1 allocation);
// x/prev stay temporal (reused). Structure otherwise identical to R2.

constexpr int C   = 16;
constexpr int GX  = 36;
constexpr int GY  = 36;
constexpr int RF  = 24;
constexpr int IMG = 64;
constexpr int GG  = GX * GY;   // 1296
constexpr int RR  = RF * RF;   // 576
constexpr int SPLIT = 4;
constexpr int CPB   = C / SPLIT;   // 4 channels per block

typedef float f4 __attribute__((ext_vector_type(4)));

__global__ __launch_bounds__(256)
void cortex_phase1(const float* __restrict__ x,
                   const float* __restrict__ prev,
                   const float* __restrict__ affW,
                   const float* __restrict__ exW,
                   const float* __restrict__ inW,
                   const int*   __restrict__ rx,
                   const int*   __restrict__ ry,
                   float* __restrict__ partial)
{
    const int bid   = blockIdx.x;
    const int ij    = bid % GG;
    const int split = bid / GG;
    const int cs    = split * CPB;
    const int i = ij / GY;
    const int j = ij - i * GY;
    const int t = threadIdx.x;

    const int rxi = rx[i];
    const int ryj = ry[j];

    float acc = 0.0f;

    // ---- Afferent: 4 channels x 144 float4 of affW (nontemporal);
    //      x via L1/L2 (temporal, reused across blocks) ----
    if (t < RR / 4) {
        const int u  = t / (RF / 4);
        const int v0 = 4 * (t - u * (RF / 4));
        f4 w[CPB];
        #pragma unroll
        for (int cc = 0; cc < CPB; ++cc) {
            const int c = cs + cc;
            w[cc] = __builtin_nontemporal_load(
                (const f4*)(affW + ((size_t)c * GG + ij) * RR) + t);
        }
        #pragma unroll
        for (int cc = 0; cc < CPB; ++cc) {
            const int c = cs + cc;
            const float* xp = x + ((c * IMG + rxi + u) * IMG + ryj + v0);
            acc = fmaf(w[cc].x, xp[0], acc);
            acc = fmaf(w[cc].y, xp[1], acc);
            acc = fmaf(w[cc].z, xp[2], acc);
            acc = fmaf(w[cc].w, xp[3], acc);
        }
    }

    // ---- Lateral: 4 channels x 324 f4 from each of exW, inW (nontemporal) ----
    float d[CPB] = {0.0f, 0.0f, 0.0f, 0.0f};
    for (int k = t; k < GG / 4; k += 256) {
        f4 e[CPB], h[CPB];
        #pragma unroll
        for (int cc = 0; cc < CPB; ++cc) {
            const size_t base = ((size_t)(cs + cc) * GG + ij) * GG;
            e[cc] = __builtin_nontemporal_load((const f4*)(exW + base) + k);
            h[cc] = __builtin_nontemporal_load((const f4*)(inW + base) + k);
        }
        #pragma unroll
        for (int cc = 0; cc < CPB; ++cc)
            d[cc] += (e[cc].x + e[cc].y + e[cc].z + e[cc].w)
                   - (h[cc].x + h[cc].y + h[cc].z + h[cc].w);
    }
    {
        float lat = 0.0f;
        #pragma unroll
        for (int cc = 0; cc < CPB; ++cc)
            lat = fmaf(prev[(cs + cc) * GG + ij], d[cc], lat);
        acc = fmaf(0.9f, lat, acc);
    }

    // ---- Block reduction ----
    for (int off = 32; off > 0; off >>= 1)
        acc += __shfl_down(acc, off, 64);

    __shared__ float sred[4];
    const int wave = t >> 6;
    const int lane = t & 63;
    if (lane == 0) sred[wave] = acc;
    __syncthreads();
    if (t == 0)
        partial[split * GG + ij] = sred[0] + sred[1] + sred[2] + sred[3];
}

__global__ __launch_bounds__(256)
void cortex_phase2(const float* __restrict__ partial, float* __restrict__ out)
{
    const int ij = blockIdx.x * blockDim.x + threadIdx.x;
    if (ij < GG) {
        const float tot = partial[ij] + partial[GG + ij]
                        + partial[2 * GG + ij] + partial[3 * GG + ij];
        const float a = fmaxf(tot, 0.0f);
        #pragma unroll
        for (int c = 0; c < C; ++c)
            out[c * GG + ij] = a;
    }
}

extern "C" void kernel_launch(void* const* d_in, const int* in_sizes, int n_in,
                              void* d_out, int out_size, void* d_ws, size_t ws_size,
                              hipStream_t stream) {
    const float* x     = (const float*)d_in[0];
    const float* prev  = (const float*)d_in[1];
    const float* affW  = (const float*)d_in[2];
    const float* exW   = (const float*)d_in[3];
    const float* inW   = (const float*)d_in[4];
    const int*   rx    = (const int*)d_in[5];
    const int*   ry    = (const int*)d_in[6];
    float* out     = (float*)d_out;
    float* partial = (float*)d_ws;   // SPLIT * GG floats

    cortex_phase1<<<GG * SPLIT, 256, 0, stream>>>(x, prev, affW, exW, inW, rx, ry, partial);
    cortex_phase2<<<(GG + 255) / 256, 256, 0, stream>>>(partial, out);
}